// Round 1
// baseline (304.694 us; speedup 1.0000x reference)
//
#include <hip/hip_runtime.h>
#include <hip/hip_bf16.h>
#include <math.h>

#define EPSF 1e-5f

constexpr int D = 128;   // feature dim
constexpr int K = 128;   // centroids
constexpr int TILE_ROWS = 64;        // 4 waves x 16 rows per tile
constexpr int BPITCH = 272;          // LDS row pitch (bytes): 4*m%32 start banks -> 2-way (free)
constexpr int NBG = 1024;            // persistent grid: exactly 4 blocks/CU on 256 CUs

typedef __bf16 bf16x8 __attribute__((ext_vector_type(8)));
typedef float  f32x4  __attribute__((ext_vector_type(4)));

// ---------------- kernel 1: centroid exp-map -> bf16 + c2 ----------------
__global__ __launch_bounds__(64) void prep_kernel(const float* __restrict__ w,
                                                  __bf16* __restrict__ crb,
                                                  float* __restrict__ c2) {
    int k = blockIdx.x;
    int t = threadIdx.x;
    float a = w[k * D + t];
    float b = w[k * D + t + 64];
    float ss = a * a + b * b;
#pragma unroll
    for (int off = 1; off < 64; off <<= 1)
        ss += __shfl_xor(ss, off, 64);
    float nrm   = sqrtf(ss);
    float nclip = fmaxf(nrm, EPSF);
    float targ  = fminf(nclip, 15.0f);
    float th    = tanhf(targ);
    float s     = th / nclip;
    crb[k * D + t]      = (__bf16)(a * s);
    crb[k * D + t + 64] = (__bf16)(b * s);
    if (t == 0) {
        float cn = s * nrm;
        c2[k] = cn * cn;
    }
}

// ---------------- kernel 2: persistent barrier-free MFMA distance ----------------
// 1024 blocks (4/CU, fully co-resident). B tile staged in LDS ONCE per block.
// Each wave owns 16 rows per tile and grid-strides over tiles with NO barriers:
// x2/mask exchanged via intra-wave shuffles, c2 held in registers, column sums
// accumulated in registers across tiles. Next tile's x loads are issued right
// after the MFMAs so HBM latency hides under the transcendental epilogue.
__global__ __launch_bounds__(256, 4) void main_kernel(
        const float* __restrict__ x, const float* __restrict__ mask,
        const __bf16* __restrict__ crb, const float* __restrict__ c2g,
        float* __restrict__ out_node, float* __restrict__ partial,
        float* __restrict__ maskpart, int ntiles) {
    __shared__ __align__(16) unsigned char sB[K * BPITCH];  // 34816 B
    __shared__ float sCol[4][K];
    __shared__ float sM[4];

    const int t    = threadIdx.x;
    const int wave = t >> 6;
    const int lane = t & 63;
    const int m    = lane & 15;
    const int q    = lane >> 4;
    const int bid  = blockIdx.x;
    const int stride = gridDim.x;

    // ---- stage B tile into LDS ONCE (coalesced global reads) ----
#pragma unroll
    for (int i = 0; i < 8; i++) {
        int f4  = t + 256 * i;        // 0..2047 float4s of crb
        int row = f4 >> 4;
        int c4  = f4 & 15;
        float4 v = ((const float4*)crb)[f4];
        *(float4*)(sB + row * BPITCH + c4 * 16) = v;
    }

    // ---- c2 for this lane's 8 columns, kept in registers for the whole block ----
    float c2v[8];
#pragma unroll
    for (int tk = 0; tk < 8; tk++) c2v[tk] = c2g[tk * 16 + m];

    float colsum[8] = {0.f, 0.f, 0.f, 0.f, 0.f, 0.f, 0.f, 0.f};
    float msumacc = 0.f;

    // pipeline state
    float4 xr[8];
    float  mk;
    bf16x8 av[4];
    float  x2r[4], pxr[4], mvr[4];

    auto issue_loads = [&](int tl) {
        const float* xrow = x + (size_t)(tl * TILE_ROWS + wave * 16 + m) * D + q * 8;
#pragma unroll
        for (int s = 0; s < 4; s++) {
            xr[2 * s]     = *(const float4*)(xrow + s * 32);
            xr[2 * s + 1] = *(const float4*)(xrow + s * 32 + 4);
        }
        mk = mask[tl * TILE_ROWS + wave * 16 + m];
    };

    auto finish_tile = [&]() {
        float ssq = 0.f;
#pragma unroll
        for (int s = 0; s < 4; s++) {
            float4 a0 = xr[2 * s], a1 = xr[2 * s + 1];
            ssq += a0.x*a0.x + a0.y*a0.y + a0.z*a0.z + a0.w*a0.w
                 + a1.x*a1.x + a1.y*a1.y + a1.z*a1.z + a1.w*a1.w;
            av[s][0] = (__bf16)a0.x; av[s][1] = (__bf16)a0.y;
            av[s][2] = (__bf16)a0.z; av[s][3] = (__bf16)a0.w;
            av[s][4] = (__bf16)a1.x; av[s][5] = (__bf16)a1.y;
            av[s][6] = (__bf16)a1.z; av[s][7] = (__bf16)a1.w;
        }
        // row sums across the 4 q-groups: lanes {l, l^16, l^32, l^48} share a row
        ssq += __shfl_xor(ssq, 16, 64);
        ssq += __shfl_xor(ssq, 32, 64);
        // per-tile mask sum over the wave's 16 rows (each 16-group identical)
        float mred = mk;
        mred += __shfl_xor(mred, 1, 64);
        mred += __shfl_xor(mred, 2, 64);
        mred += __shfl_xor(mred, 4, 64);
        mred += __shfl_xor(mred, 8, 64);
        msumacc += mred;
        // distribute row quantities to the lanes that own them in the C-layout
#pragma unroll
        for (int i = 0; i < 4; i++) {
            x2r[i] = __shfl(ssq, q * 4 + i, 64);
            pxr[i] = 1.0f - x2r[i];
            mvr[i] = __shfl(mk, q * 4 + i, 64);
        }
    };

    __syncthreads();   // sB published — the ONLY barrier before the epilogue

    // prologue: tile0 fully prepared
    issue_loads(bid);
    finish_tile();

    for (int tile = bid; tile < ntiles; tile += stride) {
        // ---- MFMA: B-frags from LDS (ds_read_b128, 2-way = free) ----
        f32x4 acc[8] = {};
#pragma unroll
        for (int s = 0; s < 4; s++) {
#pragma unroll
            for (int tk = 0; tk < 8; tk++) {
                bf16x8 bv = *(const bf16x8*)(sB + (tk * 16 + m) * BPITCH + q * 16 + s * 64);
                acc[tk] = __builtin_amdgcn_mfma_f32_16x16x32_bf16(av[s], bv, acc[tk], 0, 0, 0);
            }
        }

        // ---- prefetch next tile's x while the epilogue runs ----
        int next = tile + stride;
        bool more = next < ntiles;
        if (more) issue_loads(next);

        // ---- epilogue: distances, column sums, immediate streaming stores ----
        const int rowq = tile * TILE_ROWS + wave * 16 + q * 4;
        float* obase = out_node + (size_t)rowq * K + m;
#pragma unroll
        for (int tk = 0; tk < 8; tk++) {
            float c2c = c2v[tk];
            float pc  = 1.0f - c2c;
#pragma unroll
            for (int i = 0; i < 4; i++) {
                float dot = acc[tk][i];
                float sq  = fmaxf(x2r[i] + c2c - 2.0f * dot, 0.0f);
                float den = fmaxf(pxr[i] * pc, EPSF);
                float arg = fmaf(2.0f * sq, __builtin_amdgcn_rcpf(den), 1.0f);
                arg = fmaxf(arg, 1.0f + 1e-7f);
                float dist = __logf(arg + __builtin_amdgcn_sqrtf(fmaf(arg, arg, -1.0f)));
                float val = dist * mvr[i];
                colsum[tk] += val;
                __builtin_nontemporal_store(val, obase + (size_t)i * K + tk * 16);
            }
        }

        // ---- convert prefetched x for the next iteration ----
        if (more) finish_tile();
    }

    // ---- block epilogue: cross-wave column reduce (single barrier) ----
#pragma unroll
    for (int tk = 0; tk < 8; tk++) {
        colsum[tk] += __shfl_xor(colsum[tk], 16, 64);
        colsum[tk] += __shfl_xor(colsum[tk], 32, 64);
    }
    if (lane < 16) {
#pragma unroll
        for (int tk = 0; tk < 8; tk++)
            sCol[wave][tk * 16 + lane] = colsum[tk];
    }
    if (lane == 0) sM[wave] = msumacc;

    __syncthreads();   // only LDS writes pending -> cheap drain

    if (t < K)
        partial[(size_t)bid * K + t] =
            sCol[0][t] + sCol[1][t] + sCol[2][t] + sCol[3][t];
    if (t == 0)
        maskpart[bid] = sM[0] + sM[1] + sM[2] + sM[3];
}

// ---------------- kernel 3: column reduce + divide by mask sum ----------------
__global__ __launch_bounds__(256) void reduce_kernel(
        const float* __restrict__ partial, const float* __restrict__ maskpart,
        float* __restrict__ out_graph, int NB) {
    int k = blockIdx.x;
    int t = threadIdx.x;
    float s = 0.f, mm = 0.f;
    for (int b = t; b < NB; b += 256) {
        s  += partial[(size_t)b * K + k];
        mm += maskpart[b];
    }
#pragma unroll
    for (int off = 1; off < 64; off <<= 1) {
        s  += __shfl_xor(s, off, 64);
        mm += __shfl_xor(mm, off, 64);
    }
    __shared__ float rs[4], rm[4];
    int w = t >> 6;
    if ((t & 63) == 0) { rs[w] = s; rm[w] = mm; }
    __syncthreads();
    if (t == 0) {
        float st = rs[0] + rs[1] + rs[2] + rs[3];
        float mt = rm[0] + rm[1] + rm[2] + rm[3];
        out_graph[k] = st / mt;
    }
}

extern "C" void kernel_launch(void* const* d_in, const int* in_sizes, int n_in,
                              void* d_out, int out_size, void* d_ws, size_t ws_size,
                              hipStream_t stream) {
    const float* node = (const float*)d_in[0];   // [N, D]
    const float* mask = (const float*)d_in[1];   // [N, 1]
    const float* w    = (const float*)d_in[2];   // [K, D]
    float* out = (float*)d_out;

    int N      = in_sizes[0] / D;                // 200000
    int ntiles = N / TILE_ROWS;                  // 3125 (exact)
    int nbg    = NBG < ntiles ? NBG : ntiles;    // 1024 persistent blocks

    // ws layout: crb bf16[K*D] | c2[K] | partial[nbg*K] | maskpart[nbg]
    __bf16* crb     = (__bf16*)d_ws;
    float* c2       = (float*)(crb + K * D);
    float* partial  = c2 + K;
    float* maskpart = partial + (size_t)nbg * K;

    float* out_graph = out;        // [K]
    float* out_node  = out + K;    // [N, K]

    prep_kernel<<<K, 64, 0, stream>>>(w, crb, c2);
    main_kernel<<<nbg, 256, 0, stream>>>(node, mask, crb, c2, out_node,
                                         partial, maskpart, ntiles);
    reduce_kernel<<<K, 256, 0, stream>>>(partial, maskpart, out_graph, nbg);
}

// Round 2
// 286.808 us; speedup vs baseline: 1.0624x; 1.0624x over previous
//
#include <hip/hip_runtime.h>
#include <hip/hip_bf16.h>
#include <math.h>

#define EPSF 1e-5f

constexpr int D = 128;   // feature dim
constexpr int K = 128;   // centroids
constexpr int TILE_ROWS = 64;        // 4 waves x 16 rows per tile
constexpr int BPITCH = 272;          // LDS row pitch (bytes): 4*m%32 start banks -> 2-way (free)
constexpr int NBG = 1024;            // persistent grid: exactly 4 blocks/CU on 256 CUs

typedef __bf16 bf16x8 __attribute__((ext_vector_type(8)));
typedef float  f32x4  __attribute__((ext_vector_type(4)));

// ---------------- kernel 1: centroid exp-map -> bf16 + c2 ----------------
__global__ __launch_bounds__(64) void prep_kernel(const float* __restrict__ w,
                                                  __bf16* __restrict__ crb,
                                                  float* __restrict__ c2) {
    int k = blockIdx.x;
    int t = threadIdx.x;
    float a = w[k * D + t];
    float b = w[k * D + t + 64];
    float ss = a * a + b * b;
#pragma unroll
    for (int off = 1; off < 64; off <<= 1)
        ss += __shfl_xor(ss, off, 64);
    float nrm   = sqrtf(ss);
    float nclip = fmaxf(nrm, EPSF);
    float targ  = fminf(nclip, 15.0f);
    float th    = tanhf(targ);
    float s     = th / nclip;
    crb[k * D + t]      = (__bf16)(a * s);
    crb[k * D + t + 64] = (__bf16)(b * s);
    if (t == 0) {
        float cn = s * nrm;
        c2[k] = cn * cn;
    }
}

// ---------------- kernel 2: persistent barrier-free MFMA distance ----------------
// 1024 blocks (4/CU, fully co-resident). B tile staged in LDS ONCE per block.
// Each wave owns 16 rows per tile and grid-strides over tiles with NO barriers.
// CRITICAL (R1 lesson): out_node stores must be issued as one tight burst per
// tile — interleaving the 64B-chunk nontemporal stores with epilogue compute
// defeats write-combining and triples HBM traffic (RMW partial lines).
__global__ __launch_bounds__(256, 4) void main_kernel(
        const float* __restrict__ x, const float* __restrict__ mask,
        const __bf16* __restrict__ crb, const float* __restrict__ c2g,
        float* __restrict__ out_node, float* __restrict__ partial,
        float* __restrict__ maskpart, int ntiles) {
    __shared__ __align__(16) unsigned char sB[K * BPITCH];  // 34816 B
    __shared__ float sCol[4][K];
    __shared__ float sM[4];

    const int t    = threadIdx.x;
    const int wave = t >> 6;
    const int lane = t & 63;
    const int m    = lane & 15;
    const int q    = lane >> 4;
    const int bid  = blockIdx.x;
    const int stride = gridDim.x;

    // ---- stage B tile into LDS ONCE (coalesced global reads) ----
#pragma unroll
    for (int i = 0; i < 8; i++) {
        int f4  = t + 256 * i;        // 0..2047 float4s of crb
        int row = f4 >> 4;
        int c4  = f4 & 15;
        float4 v = ((const float4*)crb)[f4];
        *(float4*)(sB + row * BPITCH + c4 * 16) = v;
    }

    // ---- c2 for this lane's 8 columns, kept in registers for the whole block ----
    float c2v[8];
#pragma unroll
    for (int tk = 0; tk < 8; tk++) c2v[tk] = c2g[tk * 16 + m];

    float colsum[8] = {0.f, 0.f, 0.f, 0.f, 0.f, 0.f, 0.f, 0.f};
    float msumacc = 0.f;

    // pipeline state
    float4 xr[8];
    float  mk;
    bf16x8 av[4];
    float  x2r[4], pxr[4], mvr[4];

    auto issue_loads = [&](int tl) {
        const float* xrow = x + (size_t)(tl * TILE_ROWS + wave * 16 + m) * D + q * 8;
#pragma unroll
        for (int s = 0; s < 4; s++) {
            xr[2 * s]     = *(const float4*)(xrow + s * 32);
            xr[2 * s + 1] = *(const float4*)(xrow + s * 32 + 4);
        }
        mk = mask[tl * TILE_ROWS + wave * 16 + m];
    };

    auto finish_tile = [&]() {
        float ssq = 0.f;
#pragma unroll
        for (int s = 0; s < 4; s++) {
            float4 a0 = xr[2 * s], a1 = xr[2 * s + 1];
            ssq += a0.x*a0.x + a0.y*a0.y + a0.z*a0.z + a0.w*a0.w
                 + a1.x*a1.x + a1.y*a1.y + a1.z*a1.z + a1.w*a1.w;
            av[s][0] = (__bf16)a0.x; av[s][1] = (__bf16)a0.y;
            av[s][2] = (__bf16)a0.z; av[s][3] = (__bf16)a0.w;
            av[s][4] = (__bf16)a1.x; av[s][5] = (__bf16)a1.y;
            av[s][6] = (__bf16)a1.z; av[s][7] = (__bf16)a1.w;
        }
        // row sums across the 4 q-groups: lanes {l, l^16, l^32, l^48} share a row
        ssq += __shfl_xor(ssq, 16, 64);
        ssq += __shfl_xor(ssq, 32, 64);
        // per-tile mask sum over the wave's 16 rows (each 16-group identical)
        float mred = mk;
        mred += __shfl_xor(mred, 1, 64);
        mred += __shfl_xor(mred, 2, 64);
        mred += __shfl_xor(mred, 4, 64);
        mred += __shfl_xor(mred, 8, 64);
        msumacc += mred;
        // distribute row quantities to the lanes that own them in the C-layout
#pragma unroll
        for (int i = 0; i < 4; i++) {
            x2r[i] = __shfl(ssq, q * 4 + i, 64);
            pxr[i] = 1.0f - x2r[i];
            mvr[i] = __shfl(mk, q * 4 + i, 64);
        }
    };

    __syncthreads();   // sB published — the ONLY barrier before the epilogue

    // prologue: tile0 fully prepared
    issue_loads(bid);
    finish_tile();

    for (int tile = bid; tile < ntiles; tile += stride) {
        // ---- MFMA: B-frags from LDS (ds_read_b128, 2-way = free) ----
        f32x4 acc[8] = {};
#pragma unroll
        for (int s = 0; s < 4; s++) {
#pragma unroll
            for (int tk = 0; tk < 8; tk++) {
                bf16x8 bv = *(const bf16x8*)(sB + (tk * 16 + m) * BPITCH + q * 16 + s * 64);
                acc[tk] = __builtin_amdgcn_mfma_f32_16x16x32_bf16(av[s], bv, acc[tk], 0, 0, 0);
            }
        }

        // ---- prefetch next tile's x while the epilogue runs ----
        int next = tile + stride;
        bool more = next < ntiles;
        if (more) issue_loads(next);

        // ---- epilogue: distances into REGISTERS + column partial sums ----
        float dv[8][4];
#pragma unroll
        for (int tk = 0; tk < 8; tk++) {
            float c2c = c2v[tk];
            float pc  = 1.0f - c2c;
#pragma unroll
            for (int i = 0; i < 4; i++) {
                float dot = acc[tk][i];
                float sq  = fmaxf(x2r[i] + c2c - 2.0f * dot, 0.0f);
                float den = fmaxf(pxr[i] * pc, EPSF);
                float arg = fmaf(2.0f * sq, __builtin_amdgcn_rcpf(den), 1.0f);
                arg = fmaxf(arg, 1.0f + 1e-7f);
                float dist = __logf(arg + __builtin_amdgcn_sqrtf(fmaf(arg, arg, -1.0f)));
                float val = dist * mvr[i];
                dv[tk][i] = val;
                colsum[tk] += val;
            }
        }

        // ---- store burst: all 32 nontemporal stores back-to-back so the
        //      64B chunks of each 128B line merge in the write path ----
        const int rowq = tile * TILE_ROWS + wave * 16 + q * 4;
        float* obase = out_node + (size_t)rowq * K + m;
#pragma unroll
        for (int tk = 0; tk < 8; tk++) {
#pragma unroll
            for (int i = 0; i < 4; i++) {
                __builtin_nontemporal_store(dv[tk][i], obase + (size_t)i * K + tk * 16);
            }
        }

        // ---- convert prefetched x for the next iteration ----
        if (more) finish_tile();
    }

    // ---- block epilogue: cross-wave column reduce (single barrier) ----
#pragma unroll
    for (int tk = 0; tk < 8; tk++) {
        colsum[tk] += __shfl_xor(colsum[tk], 16, 64);
        colsum[tk] += __shfl_xor(colsum[tk], 32, 64);
    }
    if (lane < 16) {
#pragma unroll
        for (int tk = 0; tk < 8; tk++)
            sCol[wave][tk * 16 + lane] = colsum[tk];
    }
    if (lane == 0) sM[wave] = msumacc;

    __syncthreads();   // only LDS writes pending -> cheap drain

    if (t < K)
        partial[(size_t)bid * K + t] =
            sCol[0][t] + sCol[1][t] + sCol[2][t] + sCol[3][t];
    if (t == 0)
        maskpart[bid] = sM[0] + sM[1] + sM[2] + sM[3];
}

// ---------------- kernel 3: column reduce + divide by mask sum ----------------
__global__ __launch_bounds__(256) void reduce_kernel(
        const float* __restrict__ partial, const float* __restrict__ maskpart,
        float* __restrict__ out_graph, int NB) {
    int k = blockIdx.x;
    int t = threadIdx.x;
    float s = 0.f, mm = 0.f;
    for (int b = t; b < NB; b += 256) {
        s  += partial[(size_t)b * K + k];
        mm += maskpart[b];
    }
#pragma unroll
    for (int off = 1; off < 64; off <<= 1) {
        s  += __shfl_xor(s, off, 64);
        mm += __shfl_xor(mm, off, 64);
    }
    __shared__ float rs[4], rm[4];
    int w = t >> 6;
    if ((t & 63) == 0) { rs[w] = s; rm[w] = mm; }
    __syncthreads();
    if (t == 0) {
        float st = rs[0] + rs[1] + rs[2] + rs[3];
        float mt = rm[0] + rm[1] + rm[2] + rm[3];
        out_graph[k] = st / mt;
    }
}

extern "C" void kernel_launch(void* const* d_in, const int* in_sizes, int n_in,
                              void* d_out, int out_size, void* d_ws, size_t ws_size,
                              hipStream_t stream) {
    const float* node = (const float*)d_in[0];   // [N, D]
    const float* mask = (const float*)d_in[1];   // [N, 1]
    const float* w    = (const float*)d_in[2];   // [K, D]
    float* out = (float*)d_out;

    int N      = in_sizes[0] / D;                // 200000
    int ntiles = N / TILE_ROWS;                  // 3125 (exact)
    int nbg    = NBG < ntiles ? NBG : ntiles;    // 1024 persistent blocks

    // ws layout: crb bf16[K*D] | c2[K] | partial[nbg*K] | maskpart[nbg]
    __bf16* crb     = (__bf16*)d_ws;
    float* c2       = (float*)(crb + K * D);
    float* partial  = c2 + K;
    float* maskpart = partial + (size_t)nbg * K;

    float* out_graph = out;        // [K]
    float* out_node  = out + K;    // [N, K]

    prep_kernel<<<K, 64, 0, stream>>>(w, crb, c2);
    main_kernel<<<nbg, 256, 0, stream>>>(node, mask, crb, c2, out_node,
                                         partial, maskpart, ntiles);
    reduce_kernel<<<K, 256, 0, stream>>>(partial, maskpart, out_graph, nbg);
}

// Round 3
// 256.148 us; speedup vs baseline: 1.1895x; 1.1197x over previous
//
#include <hip/hip_runtime.h>
#include <hip/hip_bf16.h>
#include <math.h>

#define EPSF 1e-5f

constexpr int D = 128;   // feature dim
constexpr int K = 128;   // centroids
constexpr int TILE_ROWS = 64;        // 4 waves x 16 rows per tile
constexpr int BPITCH = 272;          // LDS row pitch (bytes): 4*m%32 start banks -> 2-way (free)
constexpr int NBG = 1024;            // persistent grid: exactly 4 blocks/CU on 256 CUs

typedef __bf16 bf16x8 __attribute__((ext_vector_type(8)));
typedef float  f32x4  __attribute__((ext_vector_type(4)));

// ---------------- kernel 1: centroid exp-map -> bf16 + c2 ----------------
__global__ __launch_bounds__(64) void prep_kernel(const float* __restrict__ w,
                                                  __bf16* __restrict__ crb,
                                                  float* __restrict__ c2) {
    int k = blockIdx.x;
    int t = threadIdx.x;
    float a = w[k * D + t];
    float b = w[k * D + t + 64];
    float ss = a * a + b * b;
#pragma unroll
    for (int off = 1; off < 64; off <<= 1)
        ss += __shfl_xor(ss, off, 64);
    float nrm   = sqrtf(ss);
    float nclip = fmaxf(nrm, EPSF);
    float targ  = fminf(nclip, 15.0f);
    float th    = tanhf(targ);
    float s     = th / nclip;
    crb[k * D + t]      = (__bf16)(a * s);
    crb[k * D + t + 64] = (__bf16)(b * s);
    if (t == 0) {
        float cn = s * nrm;
        c2[k] = cn * cn;
    }
}

// ---------------- kernel 2: persistent barrier-free MFMA distance ----------------
// 1024 blocks (4/CU, co-resident). B staged in LDS once. NO cross-tile
// prefetch (R1/R2 lesson: 32 prefetch regs live across the transcendental
// epilogue spilled to scratch -> +345MB HBM traffic). Latency hiding is
// pure TLP: 16 barrier-free independent waves per CU.
__global__ __launch_bounds__(256, 4) void main_kernel(
        const float* __restrict__ x, const float* __restrict__ mask,
        const __bf16* __restrict__ crb, const float* __restrict__ c2g,
        float* __restrict__ out_node, float* __restrict__ partial,
        float* __restrict__ maskpart, int ntiles) {
    __shared__ __align__(16) unsigned char sB[K * BPITCH];  // 34816 B
    __shared__ float sC2[K];
    __shared__ float sCol[4][K];
    __shared__ float sM[4];

    const int t    = threadIdx.x;
    const int wave = t >> 6;
    const int lane = t & 63;
    const int m    = lane & 15;
    const int q    = lane >> 4;
    const int bid  = blockIdx.x;
    const int stride = gridDim.x;

    // ---- stage B tile + c2 into LDS ONCE (coalesced global reads) ----
#pragma unroll
    for (int i = 0; i < 8; i++) {
        int f4  = t + 256 * i;        // 0..2047 float4s of crb
        int row = f4 >> 4;
        int c4  = f4 & 15;
        float4 v = ((const float4*)crb)[f4];
        *(float4*)(sB + row * BPITCH + c4 * 16) = v;
    }
    if (t < K) sC2[t] = c2g[t];

    float colsum[8] = {0.f, 0.f, 0.f, 0.f, 0.f, 0.f, 0.f, 0.f};
    float msumacc = 0.f;

    __syncthreads();   // sB/sC2 published — the ONLY barrier before block end

    for (int tile = bid; tile < ntiles; tile += stride) {
        // ---- load this tile's x rows (8 x float4 per lane) ----
        const float* xrow = x + (size_t)(tile * TILE_ROWS + wave * 16 + m) * D + q * 8;
        float4 xr[8];
#pragma unroll
        for (int s = 0; s < 4; s++) {
            xr[2 * s]     = *(const float4*)(xrow + s * 32);
            xr[2 * s + 1] = *(const float4*)(xrow + s * 32 + 4);
        }
        float mk = mask[tile * TILE_ROWS + wave * 16 + m];

        // ---- row sum-sq + bf16 convert (xr dies here) ----
        float ssq = 0.f;
        bf16x8 av[4];
#pragma unroll
        for (int s = 0; s < 4; s++) {
            float4 a0 = xr[2 * s], a1 = xr[2 * s + 1];
            ssq += a0.x*a0.x + a0.y*a0.y + a0.z*a0.z + a0.w*a0.w
                 + a1.x*a1.x + a1.y*a1.y + a1.z*a1.z + a1.w*a1.w;
            av[s][0] = (__bf16)a0.x; av[s][1] = (__bf16)a0.y;
            av[s][2] = (__bf16)a0.z; av[s][3] = (__bf16)a0.w;
            av[s][4] = (__bf16)a1.x; av[s][5] = (__bf16)a1.y;
            av[s][6] = (__bf16)a1.z; av[s][7] = (__bf16)a1.w;
        }
        // lanes {l, l^16, l^32, l^48} hold partials of the same row
        ssq += __shfl_xor(ssq, 16, 64);
        ssq += __shfl_xor(ssq, 32, 64);
        // per-tile mask sum over the wave's 16 rows
        float mred = mk;
        mred += __shfl_xor(mred, 1, 64);
        mred += __shfl_xor(mred, 2, 64);
        mred += __shfl_xor(mred, 4, 64);
        mred += __shfl_xor(mred, 8, 64);
        msumacc += mred;
        // distribute row quantities to C-layout owner lanes
        float x2r[4], pxr[4], mvr[4];
#pragma unroll
        for (int i = 0; i < 4; i++) {
            x2r[i] = __shfl(ssq, q * 4 + i, 64);
            pxr[i] = 1.0f - x2r[i];
            mvr[i] = __shfl(mk, q * 4 + i, 64);
        }

        // ---- MFMA: B-frags from LDS (ds_read_b128, 2-way = free) ----
        f32x4 acc[8] = {};
#pragma unroll
        for (int s = 0; s < 4; s++) {
#pragma unroll
            for (int tk = 0; tk < 8; tk++) {
                bf16x8 bv = *(const bf16x8*)(sB + (tk * 16 + m) * BPITCH + q * 16 + s * 64);
                acc[tk] = __builtin_amdgcn_mfma_f32_16x16x32_bf16(av[s], bv, acc[tk], 0, 0, 0);
            }
        }

        // ---- epilogue in two halves (liveness: dv capped at 16 regs).
        //      Half h covers tk = 4h..4h+3 -> 128B line pairs (2j,2j+1)
        //      complete within one burst, preserving write-combining. ----
        const int rowq = tile * TILE_ROWS + wave * 16 + q * 4;
        float* obase = out_node + (size_t)rowq * K + m;
#pragma unroll
        for (int h = 0; h < 2; h++) {
            float dv[4][4];
#pragma unroll
            for (int tk2 = 0; tk2 < 4; tk2++) {
                int tk = h * 4 + tk2;
                float c2c = sC2[tk * 16 + m];
                float pc  = 1.0f - c2c;
#pragma unroll
                for (int i = 0; i < 4; i++) {
                    float dot = acc[tk][i];
                    float sq  = fmaxf(x2r[i] + c2c - 2.0f * dot, 0.0f);
                    float den = fmaxf(pxr[i] * pc, EPSF);
                    float arg = fmaf(2.0f * sq, __builtin_amdgcn_rcpf(den), 1.0f);
                    arg = fmaxf(arg, 1.0f + 1e-7f);
                    float dist = __logf(arg + __builtin_amdgcn_sqrtf(fmaf(arg, arg, -1.0f)));
                    float val = dist * mvr[i];
                    dv[tk2][i] = val;
                    colsum[tk] += val;
                }
            }
            // tight 16-store burst
#pragma unroll
            for (int tk2 = 0; tk2 < 4; tk2++) {
                int tk = h * 4 + tk2;
#pragma unroll
                for (int i = 0; i < 4; i++)
                    __builtin_nontemporal_store(dv[tk2][i], obase + (size_t)i * K + tk * 16);
            }
        }
    }

    // ---- block epilogue: cross-wave column reduce (single barrier) ----
#pragma unroll
    for (int tk = 0; tk < 8; tk++) {
        colsum[tk] += __shfl_xor(colsum[tk], 16, 64);
        colsum[tk] += __shfl_xor(colsum[tk], 32, 64);
    }
    if (lane < 16) {
#pragma unroll
        for (int tk = 0; tk < 8; tk++)
            sCol[wave][tk * 16 + lane] = colsum[tk];
    }
    if (lane == 0) sM[wave] = msumacc;

    __syncthreads();   // only LDS writes pending -> cheap drain

    if (t < K)
        partial[(size_t)bid * K + t] =
            sCol[0][t] + sCol[1][t] + sCol[2][t] + sCol[3][t];
    if (t == 0)
        maskpart[bid] = sM[0] + sM[1] + sM[2] + sM[3];
}

// ---------------- kernel 3: column reduce + divide by mask sum ----------------
__global__ __launch_bounds__(256) void reduce_kernel(
        const float* __restrict__ partial, const float* __restrict__ maskpart,
        float* __restrict__ out_graph, int NB) {
    int k = blockIdx.x;
    int t = threadIdx.x;
    float s = 0.f, mm = 0.f;
    for (int b = t; b < NB; b += 256) {
        s  += partial[(size_t)b * K + k];
        mm += maskpart[b];
    }
#pragma unroll
    for (int off = 1; off < 64; off <<= 1) {
        s  += __shfl_xor(s, off, 64);
        mm += __shfl_xor(mm, off, 64);
    }
    __shared__ float rs[4], rm[4];
    int w = t >> 6;
    if ((t & 63) == 0) { rs[w] = s; rm[w] = mm; }
    __syncthreads();
    if (t == 0) {
        float st = rs[0] + rs[1] + rs[2] + rs[3];
        float mt = rm[0] + rm[1] + rm[2] + rm[3];
        out_graph[k] = st / mt;
    }
}

extern "C" void kernel_launch(void* const* d_in, const int* in_sizes, int n_in,
                              void* d_out, int out_size, void* d_ws, size_t ws_size,
                              hipStream_t stream) {
    const float* node = (const float*)d_in[0];   // [N, D]
    const float* mask = (const float*)d_in[1];   // [N, 1]
    const float* w    = (const float*)d_in[2];   // [K, D]
    float* out = (float*)d_out;

    int N      = in_sizes[0] / D;                // 200000
    int ntiles = N / TILE_ROWS;                  // 3125 (exact)
    int nbg    = NBG < ntiles ? NBG : ntiles;    // 1024 persistent blocks

    // ws layout: crb bf16[K*D] | c2[K] | partial[nbg*K] | maskpart[nbg]
    __bf16* crb     = (__bf16*)d_ws;
    float* c2       = (float*)(crb + K * D);
    float* partial  = c2 + K;
    float* maskpart = partial + (size_t)nbg * K;

    float* out_graph = out;        // [K]
    float* out_node  = out + K;    // [N, K]

    prep_kernel<<<K, 64, 0, stream>>>(w, crb, c2);
    main_kernel<<<nbg, 256, 0, stream>>>(node, mask, crb, c2, out_node,
                                         partial, maskpart, ntiles);
    reduce_kernel<<<K, 256, 0, stream>>>(partial, maskpart, out_graph, nbg);
}

// Round 4
// 206.353 us; speedup vs baseline: 1.4766x; 1.2413x over previous
//
#include <hip/hip_runtime.h>
#include <hip/hip_bf16.h>
#include <math.h>

#define EPSF 1e-5f

constexpr int D = 128;   // feature dim
constexpr int K = 128;   // centroids
constexpr int TILE_ROWS = 64;        // 4 waves x 16 rows per tile
constexpr int BPITCH = 272;          // LDS row pitch (bytes): 4*m%32 start banks -> 2-way (free)
constexpr int NBG = 1024;            // persistent grid: exactly 4 blocks/CU on 256 CUs

typedef __bf16 bf16x8 __attribute__((ext_vector_type(8)));
typedef float  f32x4  __attribute__((ext_vector_type(4)));

// ---------------- kernel 1: centroid exp-map -> bf16 + c2 ----------------
__global__ __launch_bounds__(64) void prep_kernel(const float* __restrict__ w,
                                                  __bf16* __restrict__ crb,
                                                  float* __restrict__ c2) {
    int k = blockIdx.x;
    int t = threadIdx.x;
    float a = w[k * D + t];
    float b = w[k * D + t + 64];
    float ss = a * a + b * b;
#pragma unroll
    for (int off = 1; off < 64; off <<= 1)
        ss += __shfl_xor(ss, off, 64);
    float nrm   = sqrtf(ss);
    float nclip = fmaxf(nrm, EPSF);
    float targ  = fminf(nclip, 15.0f);
    float th    = tanhf(targ);
    float s     = th / nclip;
    crb[k * D + t]      = (__bf16)(a * s);
    crb[k * D + t + 64] = (__bf16)(b * s);
    if (t == 0) {
        float cn = s * nrm;
        c2[k] = cn * cn;
    }
}

// ---------------- kernel 2: persistent barrier-free MFMA distance ----------------
// 1024 blocks (4/CU, co-resident; LDS caps blocks/CU at 4 anyway). B staged in
// LDS once per block. Grid-stride over tiles with NO barriers in the loop.
// Lessons encoded here:
//  - R1/R2: no cross-tile register prefetch (spilled -> +300MB HBM traffic).
//  - R3: NO min-waves qualifier on __launch_bounds__ — "(256,4)" clamped the
//    allocator to 64 VGPRs and spilled ~36 dwords/thread/tile (VGPR_Count=64,
//    symmetric +120MB fetch/write). Plain (256) = R0's proven-clean allocation.
__global__ __launch_bounds__(256) void main_kernel(
        const float* __restrict__ x, const float* __restrict__ mask,
        const __bf16* __restrict__ crb, const float* __restrict__ c2g,
        float* __restrict__ out_node, float* __restrict__ partial,
        float* __restrict__ maskpart, int ntiles) {
    __shared__ __align__(16) unsigned char sB[K * BPITCH];  // 34816 B
    __shared__ float sC2[K];
    __shared__ float sCol[4][K];
    __shared__ float sM[4];

    const int t    = threadIdx.x;
    const int wave = t >> 6;
    const int lane = t & 63;
    const int m    = lane & 15;
    const int q    = lane >> 4;
    const int bid  = blockIdx.x;
    const int stride = gridDim.x;

    // ---- stage B tile + c2 into LDS ONCE (coalesced global reads) ----
#pragma unroll
    for (int i = 0; i < 8; i++) {
        int f4  = t + 256 * i;        // 0..2047 float4s of crb
        int row = f4 >> 4;
        int c4  = f4 & 15;
        float4 v = ((const float4*)crb)[f4];
        *(float4*)(sB + row * BPITCH + c4 * 16) = v;
    }
    if (t < K) sC2[t] = c2g[t];

    float colsum[8] = {0.f, 0.f, 0.f, 0.f, 0.f, 0.f, 0.f, 0.f};
    float msumacc = 0.f;

    __syncthreads();   // sB/sC2 published — the ONLY barrier before block end

    for (int tile = bid; tile < ntiles; tile += stride) {
        // ---- load this tile's x rows (8 x float4 per lane) ----
        const float* xrow = x + (size_t)(tile * TILE_ROWS + wave * 16 + m) * D + q * 8;
        float4 xr[8];
#pragma unroll
        for (int s = 0; s < 4; s++) {
            xr[2 * s]     = *(const float4*)(xrow + s * 32);
            xr[2 * s + 1] = *(const float4*)(xrow + s * 32 + 4);
        }
        float mk = mask[tile * TILE_ROWS + wave * 16 + m];

        // ---- row sum-sq + bf16 convert (xr dies here) ----
        float ssq = 0.f;
        bf16x8 av[4];
#pragma unroll
        for (int s = 0; s < 4; s++) {
            float4 a0 = xr[2 * s], a1 = xr[2 * s + 1];
            ssq += a0.x*a0.x + a0.y*a0.y + a0.z*a0.z + a0.w*a0.w
                 + a1.x*a1.x + a1.y*a1.y + a1.z*a1.z + a1.w*a1.w;
            av[s][0] = (__bf16)a0.x; av[s][1] = (__bf16)a0.y;
            av[s][2] = (__bf16)a0.z; av[s][3] = (__bf16)a0.w;
            av[s][4] = (__bf16)a1.x; av[s][5] = (__bf16)a1.y;
            av[s][6] = (__bf16)a1.z; av[s][7] = (__bf16)a1.w;
        }
        // lanes {l, l^16, l^32, l^48} hold partials of the same row
        ssq += __shfl_xor(ssq, 16, 64);
        ssq += __shfl_xor(ssq, 32, 64);
        // per-tile mask sum over the wave's 16 rows
        float mred = mk;
        mred += __shfl_xor(mred, 1, 64);
        mred += __shfl_xor(mred, 2, 64);
        mred += __shfl_xor(mred, 4, 64);
        mred += __shfl_xor(mred, 8, 64);
        msumacc += mred;
        // distribute row quantities to C-layout owner lanes
        float x2r[4], pxr[4], mvr[4];
#pragma unroll
        for (int i = 0; i < 4; i++) {
            x2r[i] = __shfl(ssq, q * 4 + i, 64);
            pxr[i] = 1.0f - x2r[i];
            mvr[i] = __shfl(mk, q * 4 + i, 64);
        }

        // ---- MFMA: B-frags from LDS (ds_read_b128, 2-way = free) ----
        f32x4 acc[8] = {};
#pragma unroll
        for (int s = 0; s < 4; s++) {
#pragma unroll
            for (int tk = 0; tk < 8; tk++) {
                bf16x8 bv = *(const bf16x8*)(sB + (tk * 16 + m) * BPITCH + q * 16 + s * 64);
                acc[tk] = __builtin_amdgcn_mfma_f32_16x16x32_bf16(av[s], bv, acc[tk], 0, 0, 0);
            }
        }

        // ---- epilogue: distances into registers + column partials (R0 body) ----
        float dv[8][4];
#pragma unroll
        for (int tk = 0; tk < 8; tk++) {
            float c2c = sC2[tk * 16 + m];
            float pc  = 1.0f - c2c;
#pragma unroll
            for (int i = 0; i < 4; i++) {
                float dot = acc[tk][i];
                float sq  = fmaxf(x2r[i] + c2c - 2.0f * dot, 0.0f);
                float den = fmaxf(pxr[i] * pc, EPSF);
                float arg = fmaf(2.0f * sq, __builtin_amdgcn_rcpf(den), 1.0f);
                arg = fmaxf(arg, 1.0f + 1e-7f);
                float dist = __logf(arg + __builtin_amdgcn_sqrtf(fmaf(arg, arg, -1.0f)));
                float val = dist * mvr[i];
                dv[tk][i] = val;
                colsum[tk] += val;
            }
        }

        // ---- single tight 32-store burst (R0-proven write-combining) ----
        const int rowq = tile * TILE_ROWS + wave * 16 + q * 4;
        float* obase = out_node + (size_t)rowq * K + m;
#pragma unroll
        for (int tk = 0; tk < 8; tk++) {
#pragma unroll
            for (int i = 0; i < 4; i++)
                __builtin_nontemporal_store(dv[tk][i], obase + (size_t)i * K + tk * 16);
        }
    }

    // ---- block epilogue: cross-wave column reduce (single barrier) ----
#pragma unroll
    for (int tk = 0; tk < 8; tk++) {
        colsum[tk] += __shfl_xor(colsum[tk], 16, 64);
        colsum[tk] += __shfl_xor(colsum[tk], 32, 64);
    }
    if (lane < 16) {
#pragma unroll
        for (int tk = 0; tk < 8; tk++)
            sCol[wave][tk * 16 + lane] = colsum[tk];
    }
    if (lane == 0) sM[wave] = msumacc;

    __syncthreads();   // only LDS writes pending -> cheap drain

    if (t < K)
        partial[(size_t)bid * K + t] =
            sCol[0][t] + sCol[1][t] + sCol[2][t] + sCol[3][t];
    if (t == 0)
        maskpart[bid] = sM[0] + sM[1] + sM[2] + sM[3];
}

// ---------------- kernel 3: column reduce + divide by mask sum ----------------
__global__ __launch_bounds__(256) void reduce_kernel(
        const float* __restrict__ partial, const float* __restrict__ maskpart,
        float* __restrict__ out_graph, int NB) {
    int k = blockIdx.x;
    int t = threadIdx.x;
    float s = 0.f, mm = 0.f;
    for (int b = t; b < NB; b += 256) {
        s  += partial[(size_t)b * K + k];
        mm += maskpart[b];
    }
#pragma unroll
    for (int off = 1; off < 64; off <<= 1) {
        s  += __shfl_xor(s, off, 64);
        mm += __shfl_xor(mm, off, 64);
    }
    __shared__ float rs[4], rm[4];
    int w = t >> 6;
    if ((t & 63) == 0) { rs[w] = s; rm[w] = mm; }
    __syncthreads();
    if (t == 0) {
        float st = rs[0] + rs[1] + rs[2] + rs[3];
        float mt = rm[0] + rm[1] + rm[2] + rm[3];
        out_graph[k] = st / mt;
    }
}

extern "C" void kernel_launch(void* const* d_in, const int* in_sizes, int n_in,
                              void* d_out, int out_size, void* d_ws, size_t ws_size,
                              hipStream_t stream) {
    const float* node = (const float*)d_in[0];   // [N, D]
    const float* mask = (const float*)d_in[1];   // [N, 1]
    const float* w    = (const float*)d_in[2];   // [K, D]
    float* out = (float*)d_out;

    int N      = in_sizes[0] / D;                // 200000
    int ntiles = N / TILE_ROWS;                  // 3125 (exact)
    int nbg    = NBG < ntiles ? NBG : ntiles;    // 1024 persistent blocks

    // ws layout: crb bf16[K*D] | c2[K] | partial[nbg*K] | maskpart[nbg]
    __bf16* crb     = (__bf16*)d_ws;
    float* c2       = (float*)(crb + K * D);
    float* partial  = c2 + K;
    float* maskpart = partial + (size_t)nbg * K;

    float* out_graph = out;        // [K]
    float* out_node  = out + K;    // [N, K]

    prep_kernel<<<K, 64, 0, stream>>>(w, crb, c2);
    main_kernel<<<nbg, 256, 0, stream>>>(node, mask, crb, c2, out_node,
                                         partial, maskpart, ntiles);
    reduce_kernel<<<K, 256, 0, stream>>>(partial, maskpart, out_graph, nbg);
}

// Round 5
// 203.540 us; speedup vs baseline: 1.4970x; 1.0138x over previous
//
#include <hip/hip_runtime.h>
#include <hip/hip_bf16.h>
#include <math.h>

#define EPSF 1e-5f

constexpr int D = 128;   // feature dim
constexpr int K = 128;   // centroids
constexpr int TILE_ROWS = 64;        // 4 waves x 16 rows per tile
constexpr int BPITCH = 272;          // LDS row pitch (bytes): 4*m%32 start banks -> 2-way (free)

typedef __bf16 bf16x8 __attribute__((ext_vector_type(8)));
typedef float  f32x4  __attribute__((ext_vector_type(4)));

// ---------------- kernel 1: centroid exp-map -> bf16 + c2 ----------------
__global__ __launch_bounds__(64) void prep_kernel(const float* __restrict__ w,
                                                  __bf16* __restrict__ crb,
                                                  float* __restrict__ c2) {
    int k = blockIdx.x;
    int t = threadIdx.x;
    float a = w[k * D + t];
    float b = w[k * D + t + 64];
    float ss = a * a + b * b;
#pragma unroll
    for (int off = 1; off < 64; off <<= 1)
        ss += __shfl_xor(ss, off, 64);
    float nrm   = sqrtf(ss);
    float nclip = fmaxf(nrm, EPSF);
    float targ  = fminf(nclip, 15.0f);
    float th    = tanhf(targ);
    float s     = th / nclip;
    crb[k * D + t]      = (__bf16)(a * s);
    crb[k * D + t + 64] = (__bf16)(b * s);
    if (t == 0) {
        float cn = s * nrm;
        c2[k] = cn * cn;
    }
}

// ---------------- kernel 2: persistent barrier-free MFMA distance ----------------
// Persistent blocks, grid sized at launch to EXACTLY fill residency (no tail).
// B staged in LDS once per block; grid-stride over tiles with NO barriers.
// Lessons encoded:
//  - R1/R2: no cross-tile register prefetch (spills -> +300MB HBM traffic).
//  - R3: no min-waves qualifier on __launch_bounds__ ("(256,4)" split the
//    unified file at 64 arch VGPRs and scratch-thrashed ~300MB).
//  - R4: VGPR=136 -> only 3 blocks/CU resident; grid 1024 (4/CU of work)
//    left a 1-block/CU tail phase costing ~50%. Grid must match residency.
__global__ __launch_bounds__(256) void main_kernel(
        const float* __restrict__ x, const float* __restrict__ mask,
        const __bf16* __restrict__ crb, const float* __restrict__ c2g,
        float* __restrict__ out_node, float* __restrict__ partial,
        float* __restrict__ maskpart, int ntiles) {
    __shared__ __align__(16) unsigned char sB[K * BPITCH];  // 34816 B
    __shared__ float sC2[K];
    __shared__ float sCol[4][K];
    __shared__ float sM[4];

    const int t    = threadIdx.x;
    const int wave = t >> 6;
    const int lane = t & 63;
    const int m    = lane & 15;
    const int q    = lane >> 4;
    const int bid  = blockIdx.x;
    const int stride = gridDim.x;

    // ---- stage B tile + c2 into LDS ONCE (coalesced global reads) ----
#pragma unroll
    for (int i = 0; i < 8; i++) {
        int f4  = t + 256 * i;        // 0..2047 float4s of crb
        int row = f4 >> 4;
        int c4  = f4 & 15;
        float4 v = ((const float4*)crb)[f4];
        *(float4*)(sB + row * BPITCH + c4 * 16) = v;
    }
    if (t < K) sC2[t] = c2g[t];

    float colsum[8] = {0.f, 0.f, 0.f, 0.f, 0.f, 0.f, 0.f, 0.f};
    float msumacc = 0.f;

    __syncthreads();   // sB/sC2 published — the ONLY barrier before block end

    for (int tile = bid; tile < ntiles; tile += stride) {
        // ---- load this tile's x rows (8 x float4 per lane) ----
        const float* xrow = x + (size_t)(tile * TILE_ROWS + wave * 16 + m) * D + q * 8;
        float4 xr[8];
#pragma unroll
        for (int s = 0; s < 4; s++) {
            xr[2 * s]     = *(const float4*)(xrow + s * 32);
            xr[2 * s + 1] = *(const float4*)(xrow + s * 32 + 4);
        }
        float mk = mask[tile * TILE_ROWS + wave * 16 + m];

        // ---- row sum-sq + bf16 convert (xr dies here) ----
        float ssq = 0.f;
        bf16x8 av[4];
#pragma unroll
        for (int s = 0; s < 4; s++) {
            float4 a0 = xr[2 * s], a1 = xr[2 * s + 1];
            ssq += a0.x*a0.x + a0.y*a0.y + a0.z*a0.z + a0.w*a0.w
                 + a1.x*a1.x + a1.y*a1.y + a1.z*a1.z + a1.w*a1.w;
            av[s][0] = (__bf16)a0.x; av[s][1] = (__bf16)a0.y;
            av[s][2] = (__bf16)a0.z; av[s][3] = (__bf16)a0.w;
            av[s][4] = (__bf16)a1.x; av[s][5] = (__bf16)a1.y;
            av[s][6] = (__bf16)a1.z; av[s][7] = (__bf16)a1.w;
        }
        // lanes {l, l^16, l^32, l^48} hold partials of the same row
        ssq += __shfl_xor(ssq, 16, 64);
        ssq += __shfl_xor(ssq, 32, 64);
        // per-tile mask sum over the wave's 16 rows
        float mred = mk;
        mred += __shfl_xor(mred, 1, 64);
        mred += __shfl_xor(mred, 2, 64);
        mred += __shfl_xor(mred, 4, 64);
        mred += __shfl_xor(mred, 8, 64);
        msumacc += mred;
        // distribute row quantities to C-layout owner lanes
        float x2r[4], pxr[4], mvr[4];
#pragma unroll
        for (int i = 0; i < 4; i++) {
            x2r[i] = __shfl(ssq, q * 4 + i, 64);
            pxr[i] = 1.0f - x2r[i];
            mvr[i] = __shfl(mk, q * 4 + i, 64);
        }

        // ---- MFMA: B-frags from LDS (ds_read_b128, 2-way = free) ----
        f32x4 acc[8] = {};
#pragma unroll
        for (int s = 0; s < 4; s++) {
#pragma unroll
            for (int tk = 0; tk < 8; tk++) {
                bf16x8 bv = *(const bf16x8*)(sB + (tk * 16 + m) * BPITCH + q * 16 + s * 64);
                acc[tk] = __builtin_amdgcn_mfma_f32_16x16x32_bf16(av[s], bv, acc[tk], 0, 0, 0);
            }
        }

        // ---- epilogue: distances into registers + column partials ----
        float dv[8][4];
#pragma unroll
        for (int tk = 0; tk < 8; tk++) {
            float c2c = sC2[tk * 16 + m];
            float pc  = 1.0f - c2c;
#pragma unroll
            for (int i = 0; i < 4; i++) {
                float dot = acc[tk][i];
                float sq  = fmaxf(x2r[i] + c2c - 2.0f * dot, 0.0f);
                float den = fmaxf(pxr[i] * pc, EPSF);
                float arg = fmaf(2.0f * sq, __builtin_amdgcn_rcpf(den), 1.0f);
                arg = fmaxf(arg, 1.0f + 1e-7f);
                float dist = __logf(arg + __builtin_amdgcn_sqrtf(fmaf(arg, arg, -1.0f)));
                float val = dist * mvr[i];
                dv[tk][i] = val;
                colsum[tk] += val;
            }
        }

        // ---- single tight 32-store burst (proven write-combining) ----
        const int rowq = tile * TILE_ROWS + wave * 16 + q * 4;
        float* obase = out_node + (size_t)rowq * K + m;
#pragma unroll
        for (int tk = 0; tk < 8; tk++) {
#pragma unroll
            for (int i = 0; i < 4; i++)
                __builtin_nontemporal_store(dv[tk][i], obase + (size_t)i * K + tk * 16);
        }
    }

    // ---- block epilogue: cross-wave column reduce (single barrier) ----
#pragma unroll
    for (int tk = 0; tk < 8; tk++) {
        colsum[tk] += __shfl_xor(colsum[tk], 16, 64);
        colsum[tk] += __shfl_xor(colsum[tk], 32, 64);
    }
    if (lane < 16) {
#pragma unroll
        for (int tk = 0; tk < 8; tk++)
            sCol[wave][tk * 16 + lane] = colsum[tk];
    }
    if (lane == 0) sM[wave] = msumacc;

    __syncthreads();   // only LDS writes pending -> cheap drain

    if (t < K)
        partial[(size_t)bid * K + t] =
            sCol[0][t] + sCol[1][t] + sCol[2][t] + sCol[3][t];
    if (t == 0)
        maskpart[bid] = sM[0] + sM[1] + sM[2] + sM[3];
}

// ---------------- kernel 3: column reduce + divide by mask sum ----------------
__global__ __launch_bounds__(256) void reduce_kernel(
        const float* __restrict__ partial, const float* __restrict__ maskpart,
        float* __restrict__ out_graph, int NB) {
    int k = blockIdx.x;
    int t = threadIdx.x;
    float s = 0.f, mm = 0.f;
    for (int b = t; b < NB; b += 256) {
        s  += partial[(size_t)b * K + k];
        mm += maskpart[b];
    }
#pragma unroll
    for (int off = 1; off < 64; off <<= 1) {
        s  += __shfl_xor(s, off, 64);
        mm += __shfl_xor(mm, off, 64);
    }
    __shared__ float rs[4], rm[4];
    int w = t >> 6;
    if ((t & 63) == 0) { rs[w] = s; rm[w] = mm; }
    __syncthreads();
    if (t == 0) {
        float st = rs[0] + rs[1] + rs[2] + rs[3];
        float mt = rm[0] + rm[1] + rm[2] + rm[3];
        out_graph[k] = st / mt;
    }
}

extern "C" void kernel_launch(void* const* d_in, const int* in_sizes, int n_in,
                              void* d_out, int out_size, void* d_ws, size_t ws_size,
                              hipStream_t stream) {
    const float* node = (const float*)d_in[0];   // [N, D]
    const float* mask = (const float*)d_in[1];   // [N, 1]
    const float* w    = (const float*)d_in[2];   // [K, D]
    float* out = (float*)d_out;

    int N      = in_sizes[0] / D;                // 200000
    int ntiles = N / TILE_ROWS;                  // 3125 (exact)

    // ---- size the persistent grid to EXACT residency (R4 lesson: no tail).
    // blocks/CU = min( waves-per-EU by VGPR (each 256-thr block = 1 wave/EU),
    //                  4 by LDS (37888B/block out of 160KB) )
    static int nbg = 0;
    if (nbg == 0) {
        int bpc = 3;  // fallback: matches measured VGPR=136 -> 3 waves/EU
        hipFuncAttributes attr;
        if (hipFuncGetAttributes(&attr, (const void*)main_kernel) == hipSuccess
            && attr.numRegs > 0) {
            int vgpr = (attr.numRegs + 7) & ~7;           // 8-granule
            int weu  = 512 / vgpr;                        // waves/EU by regs
            if (weu > 8) weu = 8;
            if (weu < 1) weu = 1;
            bpc = weu < 4 ? weu : 4;                      // LDS caps at 4
        }
        nbg = 256 * bpc;
        if (nbg > ntiles) nbg = ntiles;
    }

    // ws layout: crb bf16[K*D] | c2[K] | partial[nbg*K] | maskpart[nbg]
    __bf16* crb     = (__bf16*)d_ws;
    float* c2       = (float*)(crb + K * D);
    float* partial  = c2 + K;
    float* maskpart = partial + (size_t)nbg * K;

    float* out_graph = out;        // [K]
    float* out_node  = out + K;    // [N, K]

    prep_kernel<<<K, 64, 0, stream>>>(w, crb, c2);
    main_kernel<<<nbg, 256, 0, stream>>>(node, mask, crb, c2, out_node,
                                         partial, maskpart, ntiles);
    reduce_kernel<<<K, 256, 0, stream>>>(partial, maskpart, out_graph, nbg);
}

// Round 6
// 203.467 us; speedup vs baseline: 1.4975x; 1.0004x over previous
//
#include <hip/hip_runtime.h>
#include <hip/hip_bf16.h>
#include <math.h>

#define EPSF 1e-5f

constexpr int D = 128;   // feature dim
constexpr int K = 128;   // centroids
constexpr int TILE_ROWS = 64;        // 4 waves x 16 rows per tile
constexpr int BPITCH = 272;          // LDS row pitch (bytes): 4*m%32 start banks -> 2-way (free)

typedef __bf16 bf16x8 __attribute__((ext_vector_type(8)));
typedef float  f32x4  __attribute__((ext_vector_type(4)));

// ---------------- kernel 1: centroid exp-map -> bf16 + c2 ----------------
__global__ __launch_bounds__(64) void prep_kernel(const float* __restrict__ w,
                                                  __bf16* __restrict__ crb,
                                                  float* __restrict__ c2) {
    int k = blockIdx.x;
    int t = threadIdx.x;
    float a = w[k * D + t];
    float b = w[k * D + t + 64];
    float ss = a * a + b * b;
#pragma unroll
    for (int off = 1; off < 64; off <<= 1)
        ss += __shfl_xor(ss, off, 64);
    float nrm   = sqrtf(ss);
    float nclip = fmaxf(nrm, EPSF);
    float targ  = fminf(nclip, 15.0f);
    float th    = tanhf(targ);
    float s     = th / nclip;
    crb[k * D + t]      = (__bf16)(a * s);
    crb[k * D + t + 64] = (__bf16)(b * s);
    if (t == 0) {
        float cn = s * nrm;
        c2[k] = cn * cn;
    }
}

// ---------------- kernel 2: persistent barrier-free MFMA distance ----------------
// Persistent blocks, grid sized at launch from the kernel's ACTUAL numRegs.
// B staged in LDS once per block; grid-stride over tiles with NO barriers.
// Lessons encoded:
//  - R1/R2: no cross-tile register prefetch (spills -> +300MB HBM traffic).
//  - R3: no min-waves qualifier on __launch_bounds__ ("(256,4)" made the
//    allocator clamp to 64 arch VGPRs and scratch-thrash ~300MB).
//  - R4/R5: resident-wave count is the first-order performance knob
//    (latency-bound body). VGPR=136 capped us at 3 blocks/CU = 12 waves.
//    This version deletes dv[8][4] (distance written IN PLACE into acc)
//    to bring VGPR <= 128 so 4 blocks/CU (16 waves) fit.
__global__ __launch_bounds__(256) void main_kernel(
        const float* __restrict__ x, const float* __restrict__ mask,
        const __bf16* __restrict__ crb, const float* __restrict__ c2g,
        float* __restrict__ out_node, float* __restrict__ partial,
        float* __restrict__ maskpart, int ntiles) {
    __shared__ __align__(16) unsigned char sB[K * BPITCH];  // 34816 B
    __shared__ float sC2[K];
    __shared__ float sCol[4][K];
    __shared__ float sM[4];

    const int t    = threadIdx.x;
    const int wave = t >> 6;
    const int lane = t & 63;
    const int m    = lane & 15;
    const int q    = lane >> 4;
    const int bid  = blockIdx.x;
    const int stride = gridDim.x;

    // ---- stage B tile + c2 into LDS ONCE (coalesced global reads) ----
#pragma unroll
    for (int i = 0; i < 8; i++) {
        int f4  = t + 256 * i;        // 0..2047 float4s of crb
        int row = f4 >> 4;
        int c4  = f4 & 15;
        float4 v = ((const float4*)crb)[f4];
        *(float4*)(sB + row * BPITCH + c4 * 16) = v;
    }
    if (t < K) sC2[t] = c2g[t];

    float colsum[8] = {0.f, 0.f, 0.f, 0.f, 0.f, 0.f, 0.f, 0.f};
    float msumacc = 0.f;

    __syncthreads();   // sB/sC2 published — the ONLY barrier before block end

    for (int tile = bid; tile < ntiles; tile += stride) {
        // ---- load this tile's x rows (8 x float4 per lane) ----
        const float* xrow = x + (size_t)(tile * TILE_ROWS + wave * 16 + m) * D + q * 8;
        float4 xr[8];
#pragma unroll
        for (int s = 0; s < 4; s++) {
            xr[2 * s]     = *(const float4*)(xrow + s * 32);
            xr[2 * s + 1] = *(const float4*)(xrow + s * 32 + 4);
        }
        float mk = mask[tile * TILE_ROWS + wave * 16 + m];

        // ---- row sum-sq + bf16 convert (xr dies here) ----
        float ssq = 0.f;
        bf16x8 av[4];
#pragma unroll
        for (int s = 0; s < 4; s++) {
            float4 a0 = xr[2 * s], a1 = xr[2 * s + 1];
            ssq += a0.x*a0.x + a0.y*a0.y + a0.z*a0.z + a0.w*a0.w
                 + a1.x*a1.x + a1.y*a1.y + a1.z*a1.z + a1.w*a1.w;
            av[s][0] = (__bf16)a0.x; av[s][1] = (__bf16)a0.y;
            av[s][2] = (__bf16)a0.z; av[s][3] = (__bf16)a0.w;
            av[s][4] = (__bf16)a1.x; av[s][5] = (__bf16)a1.y;
            av[s][6] = (__bf16)a1.z; av[s][7] = (__bf16)a1.w;
        }
        // lanes {l, l^16, l^32, l^48} hold partials of the same row
        ssq += __shfl_xor(ssq, 16, 64);
        ssq += __shfl_xor(ssq, 32, 64);
        // per-tile mask sum over the wave's 16 rows
        float mred = mk;
        mred += __shfl_xor(mred, 1, 64);
        mred += __shfl_xor(mred, 2, 64);
        mred += __shfl_xor(mred, 4, 64);
        mred += __shfl_xor(mred, 8, 64);
        msumacc += mred;
        // distribute row quantities to C-layout owner lanes
        float x2r[4], pxr[4], mvr[4];
#pragma unroll
        for (int i = 0; i < 4; i++) {
            x2r[i] = __shfl(ssq, q * 4 + i, 64);
            pxr[i] = 1.0f - x2r[i];
            mvr[i] = __shfl(mk, q * 4 + i, 64);
        }

        // ---- MFMA: B-frags from LDS (ds_read_b128, 2-way = free) ----
        f32x4 acc[8] = {};
#pragma unroll
        for (int s = 0; s < 4; s++) {
#pragma unroll
            for (int tk = 0; tk < 8; tk++) {
                bf16x8 bv = *(const bf16x8*)(sB + (tk * 16 + m) * BPITCH + q * 16 + s * 64);
                acc[tk] = __builtin_amdgcn_mfma_f32_16x16x32_bf16(av[s], bv, acc[tk], 0, 0, 0);
            }
        }

        // ---- epilogue IN PLACE: acc[tk][i] := masked distance (no dv[] --
        //      saves 32 VGPRs of peak liveness; R4/R5 lesson) ----
#pragma unroll
        for (int tk = 0; tk < 8; tk++) {
            float c2c = sC2[tk * 16 + m];
            float pc  = 1.0f - c2c;
#pragma unroll
            for (int i = 0; i < 4; i++) {
                float dot = acc[tk][i];
                float sq  = fmaxf(x2r[i] + c2c - 2.0f * dot, 0.0f);
                float den = fmaxf(pxr[i] * pc, EPSF);
                float arg = fmaf(2.0f * sq, __builtin_amdgcn_rcpf(den), 1.0f);
                arg = fmaxf(arg, 1.0f + 1e-7f);
                float dist = __logf(arg + __builtin_amdgcn_sqrtf(fmaf(arg, arg, -1.0f)));
                float val = dist * mvr[i];
                acc[tk][i] = val;
                colsum[tk] += val;
            }
        }

        // ---- single tight 32-store burst (proven write-combining) ----
        const int rowq = tile * TILE_ROWS + wave * 16 + q * 4;
        float* obase = out_node + (size_t)rowq * K + m;
#pragma unroll
        for (int tk = 0; tk < 8; tk++) {
#pragma unroll
            for (int i = 0; i < 4; i++)
                __builtin_nontemporal_store(acc[tk][i], obase + (size_t)i * K + tk * 16);
        }
    }

    // ---- block epilogue: cross-wave column reduce (single barrier) ----
#pragma unroll
    for (int tk = 0; tk < 8; tk++) {
        colsum[tk] += __shfl_xor(colsum[tk], 16, 64);
        colsum[tk] += __shfl_xor(colsum[tk], 32, 64);
    }
    if (lane < 16) {
#pragma unroll
        for (int tk = 0; tk < 8; tk++)
            sCol[wave][tk * 16 + lane] = colsum[tk];
    }
    if (lane == 0) sM[wave] = msumacc;

    __syncthreads();   // only LDS writes pending -> cheap drain

    if (t < K)
        partial[(size_t)bid * K + t] =
            sCol[0][t] + sCol[1][t] + sCol[2][t] + sCol[3][t];
    if (t == 0)
        maskpart[bid] = sM[0] + sM[1] + sM[2] + sM[3];
}

// ---------------- kernel 3: column reduce + divide by mask sum ----------------
__global__ __launch_bounds__(256) void reduce_kernel(
        const float* __restrict__ partial, const float* __restrict__ maskpart,
        float* __restrict__ out_graph, int NB) {
    int k = blockIdx.x;
    int t = threadIdx.x;
    float s = 0.f, mm = 0.f;
    for (int b = t; b < NB; b += 256) {
        s  += partial[(size_t)b * K + k];
        mm += maskpart[b];
    }
#pragma unroll
    for (int off = 1; off < 64; off <<= 1) {
        s  += __shfl_xor(s, off, 64);
        mm += __shfl_xor(mm, off, 64);
    }
    __shared__ float rs[4], rm[4];
    int w = t >> 6;
    if ((t & 63) == 0) { rs[w] = s; rm[w] = mm; }
    __syncthreads();
    if (t == 0) {
        float st = rs[0] + rs[1] + rs[2] + rs[3];
        float mt = rm[0] + rm[1] + rm[2] + rm[3];
        out_graph[k] = st / mt;
    }
}

extern "C" void kernel_launch(void* const* d_in, const int* in_sizes, int n_in,
                              void* d_out, int out_size, void* d_ws, size_t ws_size,
                              hipStream_t stream) {
    const float* node = (const float*)d_in[0];   // [N, D]
    const float* mask = (const float*)d_in[1];   // [N, 1]
    const float* w    = (const float*)d_in[2];   // [K, D]
    float* out = (float*)d_out;

    int N      = in_sizes[0] / D;                // 200000
    int ntiles = N / TILE_ROWS;                  // 3125 (exact)

    // ---- size the persistent grid to EXACT residency (R4/R5 lesson).
    // blocks/CU = min( waves-per-EU by VGPR (256-thr block = 1 wave/EU each),
    //                  4 by LDS (37888B/block out of 160KB) )
    static int nbg = 0;
    if (nbg == 0) {
        int bpc = 4;  // target: VGPR <= 128 -> 4 blocks/CU
        hipFuncAttributes attr;
        if (hipFuncGetAttributes(&attr, (const void*)main_kernel) == hipSuccess
            && attr.numRegs > 0) {
            int vgpr = (attr.numRegs + 7) & ~7;           // 8-granule
            int weu  = 512 / vgpr;                        // waves/EU by regs
            if (weu > 8) weu = 8;
            if (weu < 1) weu = 1;
            bpc = weu < 4 ? weu : 4;                      // LDS caps at 4
        }
        nbg = 256 * bpc;
        if (nbg > ntiles) nbg = ntiles;
    }

    // ws layout: crb bf16[K*D] | c2[K] | partial[nbg*K] | maskpart[nbg]
    __bf16* crb     = (__bf16*)d_ws;
    float* c2       = (float*)(crb + K * D);
    float* partial  = c2 + K;
    float* maskpart = partial + (size_t)nbg * K;

    float* out_graph = out;        // [K]
    float* out_node  = out + K;    // [N, K]

    prep_kernel<<<K, 64, 0, stream>>>(w, crb, c2);
    main_kernel<<<nbg, 256, 0, stream>>>(node, mask, crb, c2, out_node,
                                         partial, maskpart, ntiles);
    reduce_kernel<<<K, 256, 0, stream>>>(partial, maskpart, out_graph, nbg);
}